// Round 3
// baseline (196.575 us; speedup 1.0000x reference)
//
#include <hip/hip_runtime.h>

// LNSNet forward, R16: fc1+fc2 fused into one kernel (fc12), killing the Cpart
// k-split HBM round-trip (8.4MB RW) and one launch boundary. fc12: 32 blocks x
// 512 thr; block = 16-row m-tile, 8 waves = 2 k-halves x 4 n-quarters; partials
// summed f32 in LDS (16KB), then bias+relu+fc2 in-block (w2 staged to LDS).
// Same f32 accumulation semantics as R15 k3+k4 (grouping differs: 2x4608 vs
// 16x576 — negligible). k0 prep + k12 conv12 bit-identical to R15.

#define B 512
#define POS 676
#define ICP 36
#define P2SZ (64*12*12)
#define SCR 26
#define IMS 58                  // LDS image row stride (ushorts), odd dwords
#define IMCOPY (54 * IMS)       // 3132 ushorts per copy
#define PL_USH (POS * ICP)      // 24336 ushorts: pool1 in LDS
#define SCRATCH_USH 6656        // max(image 2*IMCOPY+96=6360, scr 8*832=6656)

typedef unsigned short ushort_t;
typedef ushort_t ushort4v __attribute__((ext_vector_type(4)));
typedef _Float16 f16x8 __attribute__((ext_vector_type(8)));
typedef float f32x4 __attribute__((ext_vector_type(4)));

__device__ __forceinline__ ushort_t f2h(float f) {
    union { _Float16 h; ushort_t u; } a; a.h = (_Float16)f; return a.u;
}
__device__ __forceinline__ float h2f(ushort_t u) {
    union { ushort_t u; _Float16 h; } a; a.u = u; return (float)a.h;
}

#define N_WR (64 * 9 * 32)
#define WR_BLOCKS 72
#define TR_BLOCKS 128
#define FC_BLOCKS 32

// ---------------- k0: conv2-weight reorder + fc1-W transpose ----------------
__global__ __launch_bounds__(256) void prep(const float* __restrict__ c2w,
                                            const float* __restrict__ f1w,
                                            ushort_t* __restrict__ wr,
                                            ushort_t* __restrict__ wfb) {
    __shared__ float tr[64 * 145];          // 37,120 B (transpose branch only)
    int blk = blockIdx.x;
    int tid = threadIdx.x;

    if (blk < WR_BLOCKS) {
        int t = blk * 256 + tid;
        int ic  = t & 31;
        int tap = (t >> 5) % 9;
        int oc  = t / 288;
        wr[t] = f2h(c2w[oc * 288 + ic * 9 + tap]);
        return;
    }
    // ---- fc1 W transpose via LDS tile ----
    int n = blk - WR_BLOCKS;
    const float* src = f1w + (size_t)n * 9216;
#pragma unroll
    for (int i = 0; i < 36; ++i) {
        int idx = i * 256 + tid;
        int oc = idx / 144, pos = idx - oc * 144;
        tr[oc * 145 + pos] = src[idx];
    }
    __syncthreads();
    ushort_t* dst = wfb + (size_t)n * 9216;
#pragma unroll
    for (int i = 0; i < 36; ++i) {
        int idx = i * 256 + tid;
        int pos = idx >> 6, oc = idx & 63;
        dst[idx] = f2h(tr[oc * 145 + pos]);
    }
}

// ---------------- k12: fused conv1 -> pool1(LDS) -> conv2 -> pool2 ----------------
__global__ __launch_bounds__(512, 4) void conv12(const float* __restrict__ x,
                                                 const float* __restrict__ w1,
                                                 const float* __restrict__ bias1,
                                                 const ushort_t* __restrict__ wr,
                                                 const float* __restrict__ bias2,
                                                 ushort_t* __restrict__ pool2cl) {
    __shared__ ushort_t smem[PL_USH + SCRATCH_USH];   // 61,984 B -> 2 blocks/CU
    ushort_t* pl  = smem;            // pool1: [676 pos][36], cols 0..31 used
    ushort_t* img = smem + PL_USH;   // phase A image (2 col-shifted copies)

    int b   = blockIdx.x;
    int tid = threadIdx.x;
    int lane = tid & 63, wid = tid >> 6;        // 8 waves
    int quad = lane >> 4, lr = lane & 15;

    // ================= phase A: conv1 via MFMA =================
    // zero pad columns / tail (never staged; fp16-NaN safety)
    for (int i = tid; i < 54; i += 512) {
        ushort_t* r0 = img + i * IMS;
        r0[54] = 0; r0[55] = 0; r0[56] = 0; r0[57] = 0;
        ushort_t* r1 = img + IMCOPY + i * IMS;
        r1[53] = 0; r1[54] = 0; r1[55] = 0; r1[56] = 0; r1[57] = 0;
    }
    if (tid < 96) img[2 * IMCOPY + tid] = 0;

    // stage image b: fp32 -> fp16, copy0 natural, copy1 shifted left 1 col
    const float* xim = x + (size_t)b * 2916;
    for (int i = tid; i < 2916; i += 512) {
        int r = i / 54, c = i - r * 54;
        ushort_t v = f2h(xim[i]);
        img[r * IMS + c] = v;
        if (c > 0) img[IMCOPY + r * IMS + c - 1] = v;
    }

    // B-frags: w1[oc][ky=quad][kx=0..2], zeros elsewhere (incl quad==3)
    f16x8 bfrag[2];
#pragma unroll
    for (int n = 0; n < 2; ++n) {
        union { ushort_t u[8]; f16x8 v; } bu;
#pragma unroll
        for (int j = 0; j < 8; ++j) bu.u[j] = 0;
        if (quad < 3) {
            const float* wp = w1 + (n * 16 + lr) * 9 + quad * 3;
            bu.u[0] = f2h(wp[0]);
            bu.u[1] = f2h(wp[1]);
            bu.u[2] = f2h(wp[2]);
        }
        bfrag[n] = bu.v;
    }
    float bv0 = bias1[lr], bv1 = bias1[16 + lr];

    __syncthreads();

    // even lanes read copy0 at col x0+lr, odd lanes copy1 at col x0+lr-1
    int cbase = (lr & 1) ? (IMCOPY + lr - 1) : lr;

    for (int it = 0; it < 4; ++it) {
        int py = wid + it * 8;
        if (py >= 26) break;
        int y0 = 2 * py;
#pragma unroll
        for (int t = 0; t < 4; ++t) {
            int x0 = t * 16;
            int off0 = cbase + x0 + (y0 + quad) * IMS;
            int off1 = off0 + IMS;
            union { unsigned d[4]; f16x8 v; } a0, a1;
            a0.d[0] = *reinterpret_cast<const unsigned*>(&img[off0]);
            a0.d[1] = *reinterpret_cast<const unsigned*>(&img[off0 + 2]);
            a0.d[2] = a0.d[0]; a0.d[3] = a0.d[1];     // k slots 4..7: zero-weighted
            a1.d[0] = *reinterpret_cast<const unsigned*>(&img[off1]);
            a1.d[1] = *reinterpret_cast<const unsigned*>(&img[off1 + 2]);
            a1.d[2] = a1.d[0]; a1.d[3] = a1.d[1];

            f32x4 cA0 = (f32x4){0.f,0.f,0.f,0.f}, cA1 = cA0, cB0 = cA0, cB1 = cA0;
            cA0 = __builtin_amdgcn_mfma_f32_16x16x32_f16(a0.v, bfrag[0], cA0, 0, 0, 0);
            cA1 = __builtin_amdgcn_mfma_f32_16x16x32_f16(a0.v, bfrag[1], cA1, 0, 0, 0);
            cB0 = __builtin_amdgcn_mfma_f32_16x16x32_f16(a1.v, bfrag[0], cB0, 0, 0, 0);
            cB1 = __builtin_amdgcn_mfma_f32_16x16x32_f16(a1.v, bfrag[1], cB1, 0, 0, 0);

            // pool 2x2 -> write pool1 straight into LDS (ICP=36 layout)
            if (t < 3 || quad == 0) {
                int px0 = t * 8 + quad * 2;
                float u0 = fmaxf(fmaxf(cA0[0], cA0[1]), fmaxf(cB0[0], cB0[1]));
                float u1 = fmaxf(fmaxf(cA0[2], cA0[3]), fmaxf(cB0[2], cB0[3]));
                float v0 = fmaxf(fmaxf(cA1[0], cA1[1]), fmaxf(cB1[0], cB1[1]));
                float v1 = fmaxf(fmaxf(cA1[2], cA1[3]), fmaxf(cB1[2], cB1[3]));
                ushort_t* po = pl + (py * 26 + px0) * ICP;
                po[lr]            = f2h(fmaxf(u0 + bv0, 0.0f));
                po[16 + lr]       = f2h(fmaxf(v0 + bv1, 0.0f));
                po[ICP + lr]      = f2h(fmaxf(u1 + bv0, 0.0f));
                po[ICP + 16 + lr] = f2h(fmaxf(v1 + bv1, 0.0f));
            }
        }
    }

    __syncthreads();   // pool1 complete; img reads done (scratch reuse safe)

    // ================= phase B: conv2 via MFMA (3 row-chunks) =================
    int prow  = wid >> 1;
    int nhalf = wid & 1;
    const ushort_t* wb = wr + (size_t)(nhalf * 32 + lr) * 288 + quad * 8;

    int ocl = lane & 31;
    int pxh = lane >> 5;
    int oc  = nhalf * 32 + ocl;
    float bv = bias2[oc];
    ushort_t* scr = smem + PL_USH + wid * (32 * SCR);   // wave-private scratch

    for (int cc = 0; cc < 3; ++cc) {
        int ebase[3];
#pragma unroll
        for (int t = 0; t < 3; ++t) {
            int m  = t * 16 + lr;
            int yl = m / 24;
            int xx = m - yl * 24;
            ebase[t] = ((8 * cc + 2 * prow + yl) * 26 + xx) * ICP + quad * 8;
        }

        f32x4 acc[3][2];
#pragma unroll
        for (int t = 0; t < 3; ++t)
#pragma unroll
            for (int n = 0; n < 2; ++n) acc[t][n] = (f32x4){0.f, 0.f, 0.f, 0.f};

#pragma unroll
        for (int tap = 0; tap < 9; ++tap) {
            int ky = tap / 3, kx = tap % 3;
            int koff = (ky * 26 + kx) * ICP;
            f16x8 a[3];
#pragma unroll
            for (int t = 0; t < 3; ++t) {
                union { ushort4v s[2]; f16x8 v; } u;
                u.s[0] = *reinterpret_cast<const ushort4v*>(&pl[ebase[t] + koff]);
                u.s[1] = *reinterpret_cast<const ushort4v*>(&pl[ebase[t] + koff + 4]);
                a[t] = u.v;
            }
            f16x8 bf[2];
#pragma unroll
            for (int n = 0; n < 2; ++n)
                bf[n] = *reinterpret_cast<const f16x8*>(wb + (size_t)n * 16 * 288 + tap * 32);
#pragma unroll
            for (int t = 0; t < 3; ++t)
#pragma unroll
                for (int n = 0; n < 2; ++n)
                    acc[t][n] = __builtin_amdgcn_mfma_f32_16x16x32_f16(a[t], bf[n], acc[t][n], 0, 0, 0);
        }

#pragma unroll
        for (int t = 0; t < 3; ++t)
#pragma unroll
            for (int n = 0; n < 2; ++n) {
                int wocl = n * 16 + lr;
                int i0 = t * 8 + quad * 2;
                float v0 = fmaxf(acc[t][n][0], acc[t][n][1]);
                float v1 = fmaxf(acc[t][n][2], acc[t][n][3]);
                union { ushort_t u2[2]; unsigned w; } pk;
                pk.u2[0] = f2h(v0); pk.u2[1] = f2h(v1);
                *reinterpret_cast<unsigned*>(&scr[wocl * SCR + i0]) = pk.w;
            }
        __syncthreads();   // uniform; orders wave-internal cross-lane scr exchange

        const ushort_t* row = scr + ocl * SCR;
        int py = cc * 4 + prow;
        ushort_t* po = pool2cl + ((size_t)b * 144 + py * 12) * 64 + oc;
#pragma unroll
        for (int j = 0; j < 6; ++j) {
            int px = pxh * 6 + j;
            float r0 = h2f(row[px]);
            float r1 = h2f(row[px + 12]);
            po[px * 64] = f2h(fmaxf(fmaxf(r0, r1) + bv, 0.0f));
        }
    }
}

// ---------------- k34: fused fc1 (full-K per block) + fc2 ----------------
// 32 blocks x 512 thr. Block = 16 batch rows. 8 waves = 2 k-halves x 4
// n-quarters (32 oc each). Partial f32 sums meet in LDS, then bias+relu+fc2.
__global__ __launch_bounds__(512) void fc12(const ushort_t* __restrict__ A,
                                            const ushort_t* __restrict__ W,
                                            const float* __restrict__ fb1,
                                            const float* __restrict__ w2,
                                            const float* __restrict__ fb2,
                                            float* __restrict__ out) {
    __shared__ float part[2][16][128];   // 16 KB: per-k-half partials
    __shared__ float w2s[10 * 128];      // 5 KB
    int tid  = threadIdx.x;
    int lane = tid & 63, wid = tid >> 6;
    int lr   = lane & 15, quad = lane >> 4;
    int kh   = wid >> 2;            // 0..1 k-half
    int nt   = wid & 3;             // 0..3 n-quarter
    int m0   = blockIdx.x * 16;
    int n0   = nt * 32;
    int k0   = kh * 4608;

    // stage fc2 weights
    for (int i = tid; i < 1280; i += 512) w2s[i] = w2[i];

    const ushort_t* a0  = A + (size_t)(m0 + lr) * 9216 + k0 + quad * 8;
    const ushort_t* b0  = W + (size_t)(n0 + lr) * 9216 + k0 + quad * 8;
    const ushort_t* b1p = b0 + (size_t)16 * 9216;

    f32x4 acc0 = (f32x4){0.f, 0.f, 0.f, 0.f};
    f32x4 acc1 = (f32x4){0.f, 0.f, 0.f, 0.f};

#pragma unroll 4
    for (int kk = 0; kk < 144; ++kk) {
        f16x8 av  = *reinterpret_cast<const f16x8*>(a0 + kk * 32);
        f16x8 bv0 = *reinterpret_cast<const f16x8*>(b0 + kk * 32);
        f16x8 bv1 = *reinterpret_cast<const f16x8*>(b1p + kk * 32);
        acc0 = __builtin_amdgcn_mfma_f32_16x16x32_f16(av, bv0, acc0, 0, 0, 0);
        acc1 = __builtin_amdgcn_mfma_f32_16x16x32_f16(av, bv1, acc1, 0, 0, 0);
    }

    // D layout (as verified in R12 k3): m = quad*4 + r, n = lr
    int mrow = quad * 4;
#pragma unroll
    for (int r = 0; r < 4; ++r) {
        part[kh][mrow + r][n0 + lr]      = acc0[r];
        part[kh][mrow + r][n0 + 16 + lr] = acc1[r];
    }
    __syncthreads();

    // combine halves + bias + relu -> part[0]
    {
        int idx = tid * 4;                 // 512 threads x 4 = 2048 elems
        int r = idx >> 7, c = idx & 127;
        f32x4 p0 = *reinterpret_cast<const f32x4*>(&part[0][r][c]);
        f32x4 p1 = *reinterpret_cast<const f32x4*>(&part[1][r][c]);
        f32x4 bb = *reinterpret_cast<const f32x4*>(&fb1[c]);
#pragma unroll
        for (int j = 0; j < 4; ++j) p0[j] = fmaxf(p0[j] + p1[j] + bb[j], 0.0f);
        *reinterpret_cast<f32x4*>(&part[0][r][c]) = p0;
    }
    __syncthreads();

    // fc2: 160 threads, one (row, out-col) each
    if (tid < 160) {
        int r = tid & 15, o = tid >> 4;    // o in 0..9
        const float* hp = &part[0][r][0];
        const float* wp = &w2s[o * 128];
        float acc = 0.f;
#pragma unroll 8
        for (int j = 0; j < 128; ++j) acc += hp[j] * wp[j];
        out[(m0 + r) * 10 + o] = acc + fb2[o];
    }
}

extern "C" void kernel_launch(void* const* d_in, const int* in_sizes, int n_in,
                              void* d_out, int out_size, void* d_ws, size_t ws_size,
                              hipStream_t stream) {
    const float* x       = (const float*)d_in[0];
    const float* conv1_w = (const float*)d_in[1];
    const float* conv1_b = (const float*)d_in[2];
    const float* conv2_w = (const float*)d_in[3];
    const float* conv2_b = (const float*)d_in[4];
    const float* fc1_w   = (const float*)d_in[5];
    const float* fc1_b   = (const float*)d_in[6];
    const float* fc2_w   = (const float*)d_in[7];
    const float* fc2_b   = (const float*)d_in[8];
    float* out = (float*)d_out;

    char* ws = (char*)d_ws;
    ushort_t* wr = (ushort_t*)ws;
    ws += N_WR * sizeof(ushort_t) + 128;
    ushort_t* wfb = (ushort_t*)ws;
    ws += (size_t)128 * 9216 * sizeof(ushort_t) + 128;
    ushort_t* pool2cl = (ushort_t*)ws;
    ws += (size_t)B * P2SZ * sizeof(ushort_t) + 128;

    prep<<<WR_BLOCKS + TR_BLOCKS, 256, 0, stream>>>(conv2_w, fc1_w, wr, wfb);
    conv12<<<B, 512, 0, stream>>>(x, conv1_w, conv1_b, wr, conv2_b, pool2cl);
    fc12<<<FC_BLOCKS, 512, 0, stream>>>(pool2cl, wfb, fc1_b, fc2_w, fc2_b, out);
}

// Round 4
// 114.484 us; speedup vs baseline: 1.7171x; 1.7171x over previous
//
#include <hip/hip_runtime.h>

// LNSNet forward, R17: revert fc to R15 split (k3 16-way k-split + k4 reduce) —
// fc12's 32-block form was latency-bound (2.8% occupancy, 99us). conv12 opts:
// (a) phase-B per-cc __syncthreads() removed — scr is wave-private (wid*832),
//     replaced with per-wave s_waitcnt lgkmcnt(0); waves drift across cc iters
//     and overlap each other's wr-loads/MFMAs instead of rendezvousing 3x.
// (b) phase-A x staging via float4 (729 vec loads vs 2916 scalar; c==52
//     straddle split). Same rounding points everywhere -> absmax unchanged.

#define B 512
#define POS 676
#define ICP 36
#define P2SZ (64*12*12)
#define SCR 26
#define IMS 58                  // LDS image row stride (ushorts), odd dwords
#define IMCOPY (54 * IMS)       // 3132 ushorts per copy
#define PL_USH (POS * ICP)      // 24336 ushorts: pool1 in LDS
#define SCRATCH_USH 6656        // max(image 2*IMCOPY+96=6360, scr 8*832=6656)

typedef unsigned short ushort_t;
typedef ushort_t ushort4v __attribute__((ext_vector_type(4)));
typedef _Float16 f16x8 __attribute__((ext_vector_type(8)));
typedef float f32x4 __attribute__((ext_vector_type(4)));

__device__ __forceinline__ ushort_t f2h(float f) {
    union { _Float16 h; ushort_t u; } a; a.h = (_Float16)f; return a.u;
}
__device__ __forceinline__ float h2f(ushort_t u) {
    union { ushort_t u; _Float16 h; } a; a.u = u; return (float)a.h;
}

#define N_WR (64 * 9 * 32)
#define WR_BLOCKS 72
#define TR_BLOCKS 128

// ---------------- k0: conv2-weight reorder + fc1-W transpose ----------------
__global__ __launch_bounds__(256) void prep(const float* __restrict__ c2w,
                                            const float* __restrict__ f1w,
                                            ushort_t* __restrict__ wr,
                                            ushort_t* __restrict__ wfb) {
    __shared__ float tr[64 * 145];          // 37,120 B (transpose branch only)
    int blk = blockIdx.x;
    int tid = threadIdx.x;

    if (blk < WR_BLOCKS) {
        int t = blk * 256 + tid;
        int ic  = t & 31;
        int tap = (t >> 5) % 9;
        int oc  = t / 288;
        wr[t] = f2h(c2w[oc * 288 + ic * 9 + tap]);
        return;
    }
    // ---- fc1 W transpose via LDS tile ----
    int n = blk - WR_BLOCKS;
    const float* src = f1w + (size_t)n * 9216;
#pragma unroll
    for (int i = 0; i < 36; ++i) {
        int idx = i * 256 + tid;
        int oc = idx / 144, pos = idx - oc * 144;
        tr[oc * 145 + pos] = src[idx];
    }
    __syncthreads();
    ushort_t* dst = wfb + (size_t)n * 9216;
#pragma unroll
    for (int i = 0; i < 36; ++i) {
        int idx = i * 256 + tid;
        int pos = idx >> 6, oc = idx & 63;
        dst[idx] = f2h(tr[oc * 145 + pos]);
    }
}

// ---------------- k12: fused conv1 -> pool1(LDS) -> conv2 -> pool2 ----------------
__global__ __launch_bounds__(512, 4) void conv12(const float* __restrict__ x,
                                                 const float* __restrict__ w1,
                                                 const float* __restrict__ bias1,
                                                 const ushort_t* __restrict__ wr,
                                                 const float* __restrict__ bias2,
                                                 ushort_t* __restrict__ pool2cl) {
    __shared__ ushort_t smem[PL_USH + SCRATCH_USH];   // 61,984 B -> 2 blocks/CU
    ushort_t* pl  = smem;            // pool1: [676 pos][36], cols 0..31 used
    ushort_t* img = smem + PL_USH;   // phase A image (2 col-shifted copies)

    int b   = blockIdx.x;
    int tid = threadIdx.x;
    int lane = tid & 63, wid = tid >> 6;        // 8 waves
    int quad = lane >> 4, lr = lane & 15;

    // ================= phase A: conv1 via MFMA =================
    // zero pad columns / tail (never staged; fp16-NaN safety)
    for (int i = tid; i < 54; i += 512) {
        ushort_t* r0 = img + i * IMS;
        r0[54] = 0; r0[55] = 0; r0[56] = 0; r0[57] = 0;
        ushort_t* r1 = img + IMCOPY + i * IMS;
        r1[53] = 0; r1[54] = 0; r1[55] = 0; r1[56] = 0; r1[57] = 0;
    }
    if (tid < 96) img[2 * IMCOPY + tid] = 0;

    // stage image b: fp32 -> fp16 via float4 (2916 = 729 vec4; c==52 straddles)
    const float* xim = x + (size_t)b * 2916;
    for (int i = tid; i < 729; i += 512) {
        int e = i * 4;
        int r = e / 54, c = e - r * 54;        // c even
        float4 xv = *reinterpret_cast<const float4*>(&xim[e]);
        ushort_t h0 = f2h(xv.x), h1 = f2h(xv.y), h2 = f2h(xv.z), h3 = f2h(xv.w);
        if (c <= 50) {
            ushort_t* p0 = &img[r * IMS + c];
            p0[0] = h0; p0[1] = h1; p0[2] = h2; p0[3] = h3;
            ushort_t* p1 = &img[IMCOPY + r * IMS + c - 1];
            if (c > 0) p1[0] = h0;
            p1[1] = h1; p1[2] = h2; p1[3] = h3;
        } else {   // c == 52: elems (r,52),(r,53),(r+1,0),(r+1,1)
            img[r * IMS + 52] = h0;
            img[r * IMS + 53] = h1;
            img[(r + 1) * IMS + 0] = h2;
            img[(r + 1) * IMS + 1] = h3;
            img[IMCOPY + r * IMS + 51] = h0;
            img[IMCOPY + r * IMS + 52] = h1;
            img[IMCOPY + (r + 1) * IMS + 0] = h3;   // copy1[r+1][0] = v(r+1,1)
        }
    }

    // B-frags: w1[oc][ky=quad][kx=0..2], zeros elsewhere (incl quad==3)
    f16x8 bfrag[2];
#pragma unroll
    for (int n = 0; n < 2; ++n) {
        union { ushort_t u[8]; f16x8 v; } bu;
#pragma unroll
        for (int j = 0; j < 8; ++j) bu.u[j] = 0;
        if (quad < 3) {
            const float* wp = w1 + (n * 16 + lr) * 9 + quad * 3;
            bu.u[0] = f2h(wp[0]);
            bu.u[1] = f2h(wp[1]);
            bu.u[2] = f2h(wp[2]);
        }
        bfrag[n] = bu.v;
    }
    float bv0 = bias1[lr], bv1 = bias1[16 + lr];

    __syncthreads();

    // even lanes read copy0 at col x0+lr, odd lanes copy1 at col x0+lr-1
    int cbase = (lr & 1) ? (IMCOPY + lr - 1) : lr;

    for (int it = 0; it < 4; ++it) {
        int py = wid + it * 8;
        if (py >= 26) break;
        int y0 = 2 * py;
#pragma unroll
        for (int t = 0; t < 4; ++t) {
            int x0 = t * 16;
            int off0 = cbase + x0 + (y0 + quad) * IMS;
            int off1 = off0 + IMS;
            union { unsigned d[4]; f16x8 v; } a0, a1;
            a0.d[0] = *reinterpret_cast<const unsigned*>(&img[off0]);
            a0.d[1] = *reinterpret_cast<const unsigned*>(&img[off0 + 2]);
            a0.d[2] = a0.d[0]; a0.d[3] = a0.d[1];     // k slots 4..7: zero-weighted
            a1.d[0] = *reinterpret_cast<const unsigned*>(&img[off1]);
            a1.d[1] = *reinterpret_cast<const unsigned*>(&img[off1 + 2]);
            a1.d[2] = a1.d[0]; a1.d[3] = a1.d[1];

            f32x4 cA0 = (f32x4){0.f,0.f,0.f,0.f}, cA1 = cA0, cB0 = cA0, cB1 = cA0;
            cA0 = __builtin_amdgcn_mfma_f32_16x16x32_f16(a0.v, bfrag[0], cA0, 0, 0, 0);
            cA1 = __builtin_amdgcn_mfma_f32_16x16x32_f16(a0.v, bfrag[1], cA1, 0, 0, 0);
            cB0 = __builtin_amdgcn_mfma_f32_16x16x32_f16(a1.v, bfrag[0], cB0, 0, 0, 0);
            cB1 = __builtin_amdgcn_mfma_f32_16x16x32_f16(a1.v, bfrag[1], cB1, 0, 0, 0);

            // pool 2x2 -> write pool1 straight into LDS (ICP=36 layout)
            if (t < 3 || quad == 0) {
                int px0 = t * 8 + quad * 2;
                float u0 = fmaxf(fmaxf(cA0[0], cA0[1]), fmaxf(cB0[0], cB0[1]));
                float u1 = fmaxf(fmaxf(cA0[2], cA0[3]), fmaxf(cB0[2], cB0[3]));
                float v0 = fmaxf(fmaxf(cA1[0], cA1[1]), fmaxf(cB1[0], cB1[1]));
                float v1 = fmaxf(fmaxf(cA1[2], cA1[3]), fmaxf(cB1[2], cB1[3]));
                ushort_t* po = pl + (py * 26 + px0) * ICP;
                po[lr]            = f2h(fmaxf(u0 + bv0, 0.0f));
                po[16 + lr]       = f2h(fmaxf(v0 + bv1, 0.0f));
                po[ICP + lr]      = f2h(fmaxf(u1 + bv0, 0.0f));
                po[ICP + 16 + lr] = f2h(fmaxf(v1 + bv1, 0.0f));
            }
        }
    }

    __syncthreads();   // pool1 complete; img reads done (scratch reuse safe)

    // ================= phase B: conv2 via MFMA (3 row-chunks) =================
    int prow  = wid >> 1;
    int nhalf = wid & 1;
    const ushort_t* wb = wr + (size_t)(nhalf * 32 + lr) * 288 + quad * 8;

    int ocl = lane & 31;
    int pxh = lane >> 5;
    int oc  = nhalf * 32 + ocl;
    float bv = bias2[oc];
    ushort_t* scr = smem + PL_USH + wid * (32 * SCR);   // wave-private scratch

    for (int cc = 0; cc < 3; ++cc) {
        int ebase[3];
#pragma unroll
        for (int t = 0; t < 3; ++t) {
            int m  = t * 16 + lr;
            int yl = m / 24;
            int xx = m - yl * 24;
            ebase[t] = ((8 * cc + 2 * prow + yl) * 26 + xx) * ICP + quad * 8;
        }

        f32x4 acc[3][2];
#pragma unroll
        for (int t = 0; t < 3; ++t)
#pragma unroll
            for (int n = 0; n < 2; ++n) acc[t][n] = (f32x4){0.f, 0.f, 0.f, 0.f};

#pragma unroll
        for (int tap = 0; tap < 9; ++tap) {
            int ky = tap / 3, kx = tap % 3;
            int koff = (ky * 26 + kx) * ICP;
            f16x8 a[3];
#pragma unroll
            for (int t = 0; t < 3; ++t) {
                union { ushort4v s[2]; f16x8 v; } u;
                u.s[0] = *reinterpret_cast<const ushort4v*>(&pl[ebase[t] + koff]);
                u.s[1] = *reinterpret_cast<const ushort4v*>(&pl[ebase[t] + koff + 4]);
                a[t] = u.v;
            }
            f16x8 bf[2];
#pragma unroll
            for (int n = 0; n < 2; ++n)
                bf[n] = *reinterpret_cast<const f16x8*>(wb + (size_t)n * 16 * 288 + tap * 32);
#pragma unroll
            for (int t = 0; t < 3; ++t)
#pragma unroll
                for (int n = 0; n < 2; ++n)
                    acc[t][n] = __builtin_amdgcn_mfma_f32_16x16x32_f16(a[t], bf[n], acc[t][n], 0, 0, 0);
        }

        // scr is wave-private: no cross-wave barrier needed, only DS ordering
#pragma unroll
        for (int t = 0; t < 3; ++t)
#pragma unroll
            for (int n = 0; n < 2; ++n) {
                int wocl = n * 16 + lr;
                int i0 = t * 8 + quad * 2;
                float v0 = fmaxf(acc[t][n][0], acc[t][n][1]);
                float v1 = fmaxf(acc[t][n][2], acc[t][n][3]);
                union { ushort_t u2[2]; unsigned w; } pk;
                pk.u2[0] = f2h(v0); pk.u2[1] = f2h(v1);
                *reinterpret_cast<unsigned*>(&scr[wocl * SCR + i0]) = pk.w;
            }
        asm volatile("s_waitcnt lgkmcnt(0)" ::: "memory");

        const ushort_t* row = scr + ocl * SCR;
        int py = cc * 4 + prow;
        ushort_t* po = pool2cl + ((size_t)b * 144 + py * 12) * 64 + oc;
#pragma unroll
        for (int j = 0; j < 6; ++j) {
            int px = pxh * 6 + j;
            float r0 = h2f(row[px]);
            float r1 = h2f(row[px + 12]);
            po[px * 64] = f2h(fmaxf(fmaxf(r0, r1) + bv, 0.0f));
        }
        asm volatile("s_waitcnt lgkmcnt(0)" ::: "memory");   // reads drain before next cc's writes
    }
}

// ---------------- k3: fc1 fp16 MFMA, 16 K-splits ----------------
__global__ __launch_bounds__(256) void fc1_mfma(const ushort_t* __restrict__ A,
                                                 const ushort_t* __restrict__ W,
                                                 float* __restrict__ Cpart) {
    int tid = threadIdx.x;
    int lane = tid & 63, wid = tid >> 6;
    int lr = lane & 15, quad = lane >> 4;
    int w  = blockIdx.x * 4 + wid;
    int nt = w & 3;
    int ks = (w >> 2) & 15;
    int mt = w >> 6;

    int m0 = mt * 16;
    int n0 = nt * 32;
    int k0 = ks * 576 + quad * 8;
    const ushort_t* a0 = A + (size_t)(m0 + lr) * 9216 + k0;
    const ushort_t* b0 = W + (size_t)(n0 + lr) * 9216 + k0;
    const ushort_t* b1 = b0 + (size_t)16 * 9216;

    f32x4 acc0 = (f32x4){0.f, 0.f, 0.f, 0.f};
    f32x4 acc1 = (f32x4){0.f, 0.f, 0.f, 0.f};

#pragma unroll
    for (int kk = 0; kk < 18; ++kk) {
        f16x8 av  = *reinterpret_cast<const f16x8*>(a0 + kk * 32);
        f16x8 bv0 = *reinterpret_cast<const f16x8*>(b0 + kk * 32);
        f16x8 bv1 = *reinterpret_cast<const f16x8*>(b1 + kk * 32);
        acc0 = __builtin_amdgcn_mfma_f32_16x16x32_f16(av, bv0, acc0, 0, 0, 0);
        acc1 = __builtin_amdgcn_mfma_f32_16x16x32_f16(av, bv1, acc1, 0, 0, 0);
    }

    float* cp = Cpart + (size_t)ks * (512 * 128);
    int crow = m0 + quad * 4;
#pragma unroll
    for (int r = 0; r < 4; ++r) {
        cp[(size_t)(crow + r) * 128 + n0 + lr]      = acc0[r];
        cp[(size_t)(crow + r) * 128 + n0 + 16 + lr] = acc1[r];
    }
}

// ---------------- k4: fc1 reduce(16) + bias + relu + fc2 ----------------
__global__ __launch_bounds__(256) void fc1fc2(const float* __restrict__ Cpart,
                                              const float* __restrict__ b1,
                                              const float* __restrict__ w2,
                                              const float* __restrict__ b2,
                                              float* __restrict__ out) {
    __shared__ float h[2][128];
    int half = threadIdx.x >> 7;
    int k = threadIdx.x & 127;
    int b = blockIdx.x * 2 + half;
    float s = 0.f;
#pragma unroll
    for (int ks = 0; ks < 16; ++ks) s += Cpart[(size_t)ks * (512 * 128) + b * 128 + k];
    h[half][k] = fmaxf(s + b1[k], 0.0f);
    __syncthreads();
    if (k < 10) {
        const float* wp = w2 + k * 128;
        float acc = 0.f;
#pragma unroll 8
        for (int j = 0; j < 128; ++j) acc += h[half][j] * wp[j];
        out[b * 10 + k] = acc + b2[k];
    }
}

extern "C" void kernel_launch(void* const* d_in, const int* in_sizes, int n_in,
                              void* d_out, int out_size, void* d_ws, size_t ws_size,
                              hipStream_t stream) {
    const float* x       = (const float*)d_in[0];
    const float* conv1_w = (const float*)d_in[1];
    const float* conv1_b = (const float*)d_in[2];
    const float* conv2_w = (const float*)d_in[3];
    const float* conv2_b = (const float*)d_in[4];
    const float* fc1_w   = (const float*)d_in[5];
    const float* fc1_b   = (const float*)d_in[6];
    const float* fc2_w   = (const float*)d_in[7];
    const float* fc2_b   = (const float*)d_in[8];
    float* out = (float*)d_out;

    char* ws = (char*)d_ws;
    ushort_t* wr = (ushort_t*)ws;
    ws += N_WR * sizeof(ushort_t) + 128;
    ushort_t* wfb = (ushort_t*)ws;
    ws += (size_t)128 * 9216 * sizeof(ushort_t) + 128;
    ushort_t* pool2cl = (ushort_t*)ws;
    ws += (size_t)B * P2SZ * sizeof(ushort_t) + 128;
    float* Cpart = (float*)ws;
    ws += (size_t)16 * 512 * 128 * sizeof(float) + 128;

    prep<<<WR_BLOCKS + TR_BLOCKS, 256, 0, stream>>>(conv2_w, fc1_w, wr, wfb);
    conv12<<<B, 512, 0, stream>>>(x, conv1_w, conv1_b, wr, conv2_b, pool2cl);
    fc1_mfma<<<512, 256, 0, stream>>>(pool2cl, wfb, Cpart);
    fc1fc2<<<256, 256, 0, stream>>>(Cpart, fc1_b, fc2_w, fc2_b, out);
}